// Round 1
// baseline (189.859 us; speedup 1.0000x reference)
//
#include <hip/hip_runtime.h>
#include <math.h>

#define BB 16
#define NN 1024
#define GG 1024
#define NP1 1025
#define NC 3

// ---------------------------------------------------------------------------
// Kernel Z: zero the matches_gt region of d_out: elements [3, 3+16*1025*1025)
// (d_out is poisoned 0xAA before every timed launch; M is mostly zeros)
// ---------------------------------------------------------------------------
__global__ void k_zero(float* __restrict__ out) {
    const long long idx = (long long)blockIdx.x * blockDim.x + threadIdx.x;
    const long long T   = (long long)gridDim.x * blockDim.x;
    // region: [3, 16810003). Head elem 3 scalar; [4, 16810000) as float4; tail 3 scalars.
    float4* f4 = (float4*)(out + 4);
    const long long n4 = (16810000LL - 1) / 4;  // 4202499 float4s -> covers [4,16810000)
    float4 z; z.x = 0.f; z.y = 0.f; z.z = 0.f; z.w = 0.f;
    for (long long k = idx; k < n4; k += T) f4[k] = z;
    if (idx == 0) {
        out[3] = 0.f;
        out[16810000] = 0.f; out[16810001] = 0.f; out[16810002] = 0.f;
    }
}

// ---------------------------------------------------------------------------
// Kernel 1: per (sample, position-chunk): nearest GT, key packing, closs part
// grid (8, 16) x 128 threads. Each thread = one position, loops 1024 GT pts in LDS.
// All FP in explicit IEEE _rn ops to bit-match the numpy reference (argmin ties!).
// ---------------------------------------------------------------------------
__global__ __launch_bounds__(128) void k_nearest(
    const float* __restrict__ positions, const float* __restrict__ gt_pts,
    const int* __restrict__ gt_ins, const int* __restrict__ gt_order,
    const int* __restrict__ gt_type,
    int* __restrict__ key_ws, int* __restrict__ sem_ws,
    float* __restrict__ closs_part)
{
    __shared__ float2 sp[GG];
    __shared__ int sins[GG], sord[GG], styp[GG];
    __shared__ float red[128];
    const int b = blockIdx.y, chunk = blockIdx.x, tid = threadIdx.x;

    // Constants, replicating numpy's f32 op sequence exactly:
    // BX = float32(-30.0 + 0.15/2.0) [double->f32 cast], BOUND = f32(0.15f*0.5f) - BX
    const float bx0 = (float)(-30.0 + 0.15 / 2.0);
    const float bx1 = (float)(-15.0 + 0.15 / 2.0);
    const float bnd0 = __fsub_rn(__fmul_rn(0.15f, 0.5f), bx0);
    const float bnd1 = __fsub_rn(__fmul_rn(0.15f, 0.5f), bx1);
    const float tb0 = __fmul_rn(2.0f, bnd0), tb1 = __fmul_rn(2.0f, bnd1);
    // CDIST_THR = f32 norm of [1.5/(2*BOUND)]
    const float q0 = __fdiv_rn(1.5f, tb0), q1 = __fdiv_rn(1.5f, tb1);
    const float thr = __fsqrt_rn(__fadd_rn(__fmul_rn(q0, q0), __fmul_rn(q1, q1)));

    for (int g = tid; g < GG; g += 128) {
        float2 gp = ((const float2*)gt_pts)[b * GG + g];
        float2 pg;
        pg.x = __fdiv_rn(__fadd_rn(gp.x, bnd0), tb0);
        pg.y = __fdiv_rn(__fadd_rn(gp.y, bnd1), tb1);
        sp[g] = pg;
        sins[g] = gt_ins[b * GG + g];
        sord[g] = gt_order[b * GG + g];
        styp[g] = gt_type[b * GG + g];
    }
    __syncthreads();

    const int i = chunk * 128 + tid;
    float2 p = ((const float2*)positions)[b * NN + i];
    const float px = __fdiv_rn(p.x, 399.0f);
    const float py = __fdiv_rn(p.y, 199.0f);

    float best = INFINITY; int bi = 0;
    for (int g = 0; g < GG; ++g) {
        float2 pg = sp[g];
        float dx = __fsub_rn(px, pg.x);
        float dy = __fsub_rn(py, pg.y);
        float s  = __fadd_rn(__fadd_rn(__fmul_rn(dx, dx), __fmul_rn(dy, dy)), 1e-12f);
        float cd = __fsqrt_rn(s);
        if (cd < best) { best = cd; bi = g; }   // strict <: first-index wins, == np.argmin
    }
    const int ins = (best < thr) ? sins[bi] : -1;
    const int key = ((ins + 1) << 15) | (sord[bi] << 10) | i;
    key_ws[b * NN + i] = key;
    sem_ws[b * NN + i] = styp[bi];

    float2 pg = sp[bi];
    float cl = fabsf(__fsub_rn(px, pg.x)) + fabsf(__fsub_rn(py, pg.y));
    red[tid] = cl; __syncthreads();
    for (int s = 64; s > 0; s >>= 1) {
        if (tid < s) red[tid] += red[tid + s];
        __syncthreads();
    }
    if (tid == 0) closs_part[b * 8 + chunk] = red[0];
}

// ---------------------------------------------------------------------------
// Kernel 2: per sample: rank-sort keys, build edges, scatter M ones, sg,
// and reduce mloss/semloss sums. grid 16 x 1024 threads.
// Exploits: newblk == blk (each column of blk has <=1 nonzero since b=perm[1:]
// is a permutation slice), so dist_map / argmin re-selection is a no-op.
// ---------------------------------------------------------------------------
__global__ __launch_bounds__(1024) void k_assemble(
    const float* __restrict__ matches, const float* __restrict__ semantics,
    const int* __restrict__ key_ws, const int* __restrict__ sem_ws,
    float* __restrict__ out, double* __restrict__ msum, double* __restrict__ ssum)
{
    __shared__ int skey[NN];
    __shared__ int sperm[NN];
    __shared__ int stf[NN];
    __shared__ int stb[NN];
    __shared__ double red[NN];
    const int b = blockIdx.x, i = threadIdx.x;

    skey[i] = key_ws[b * NN + i];
    stf[i] = NN; stb[i] = NN;
    __syncthreads();

    const int k = skey[i];
    int rank = 0;
    #pragma unroll 8
    for (int j = 0; j < NN; ++j) rank += (skey[j] < k) ? 1 : 0;  // keys unique
    sperm[rank] = i;
    __syncthreads();

    if (i < NN - 1) {
        int a = sperm[i], c = sperm[i + 1];
        int ia = (skey[a] >> 15) - 1;
        int ic = (skey[c] >> 15) - 1;
        if (ia == ic && ia >= 0) { stf[a] = c; stb[c] = a; }
    }
    __syncthreads();

    const int jf = stf[i];   // t_fwd[i]: edge target or N
    const int jb = stb[i];   // t_back[i]: edge source or N

    float* Mb = out + 3 + (size_t)b * NP1 * NP1;
    Mb[(size_t)i * NP1 + jf] = 1.0f;                 // one 1 per row i < N
    if (jb == NN) Mb[(size_t)NN * NP1 + i] = 1.0f;   // row N: cols w/o incoming edge

    const float* mrow = matches + (size_t)b * NP1 * NP1 + (size_t)i * NP1;
    double mp = (double)mrow[jf] + (double)mrow[jb];

    const int sc = sem_ws[b * NN + i];
    double spv = (double)semantics[b * NC * NN + sc * NN + i];

    float* sg = out + 3 + (size_t)BB * NP1 * NP1 + (size_t)b * NC * NN;
    sg[0 * NN + i] = (sc == 0) ? 1.0f : 0.0f;
    sg[1 * NN + i] = (sc == 1) ? 1.0f : 0.0f;
    sg[2 * NN + i] = (sc == 2) ? 1.0f : 0.0f;

    red[i] = mp; __syncthreads();
    for (int s = 512; s > 0; s >>= 1) {
        if (i < s) red[i] += red[i + s];
        __syncthreads();
    }
    if (i == 0) msum[b] = red[0];
    __syncthreads();

    red[i] = spv; __syncthreads();
    for (int s = 512; s > 0; s >>= 1) {
        if (i < s) red[i] += red[i + s];
        __syncthreads();
    }
    if (i == 0) ssum[b] = red[0];
}

// ---------------------------------------------------------------------------
// Final: fold per-sample sums into the 3 scalar outputs.
// ---------------------------------------------------------------------------
__global__ void k_final(const float* __restrict__ closs_part,
                        const double* __restrict__ msum,
                        const double* __restrict__ ssum,
                        float* __restrict__ out)
{
    if (threadIdx.x == 0 && blockIdx.x == 0) {
        double c = 0.0;
        for (int t = 0; t < BB * 8; ++t) c += (double)closs_part[t];
        double m = 0.0, s = 0.0;
        for (int b = 0; b < BB; ++b) { m += msum[b]; s += ssum[b]; }
        out[0] = (float)(c / (2048.0 * (double)BB));
        out[1] = (float)(-m / (1024.0 * (double)BB));
        out[2] = (float)(-s / (1024.0 * (double)BB));
    }
}

extern "C" void kernel_launch(void* const* d_in, const int* in_sizes, int n_in,
                              void* d_out, int out_size, void* d_ws, size_t ws_size,
                              hipStream_t stream) {
    const float* matches   = (const float*)d_in[0];
    const float* positions = (const float*)d_in[1];
    const float* semantics = (const float*)d_in[2];
    // d_in[3] = masks (all ones, unused by the reference math)
    const float* gt_pts    = (const float*)d_in[4];
    const int*   gt_ins    = (const int*)d_in[5];
    const int*   gt_order  = (const int*)d_in[6];
    const int*   gt_type   = (const int*)d_in[7];
    float* out = (float*)d_out;

    char* ws = (char*)d_ws;
    int*    key_ws     = (int*)ws;                       // 16*1024 ints
    int*    sem_ws     = (int*)(ws + 65536);             // 16*1024 ints
    float*  closs_part = (float*)(ws + 131072);          // 128 floats
    double* msum       = (double*)(ws + 131072 + 1024);  // 16 doubles (8B aligned)
    double* ssum       = (double*)(ws + 131072 + 1024 + 128);

    hipLaunchKernelGGL(k_zero, dim3(2048), dim3(256), 0, stream, out);
    hipLaunchKernelGGL(k_nearest, dim3(8, 16), dim3(128), 0, stream,
                       positions, gt_pts, gt_ins, gt_order, gt_type,
                       key_ws, sem_ws, closs_part);
    hipLaunchKernelGGL(k_assemble, dim3(16), dim3(1024), 0, stream,
                       matches, semantics, key_ws, sem_ws, out, msum, ssum);
    hipLaunchKernelGGL(k_final, dim3(1), dim3(1), 0, stream,
                       closs_part, msum, ssum, out);
}

// Round 2
// 154.003 us; speedup vs baseline: 1.2328x; 1.2328x over previous
//
#include <hip/hip_runtime.h>
#include <math.h>

#define BB 16
#define NN 1024
#define GG 1024
#define NP1 1025
#define NC 3

// Constants replicated with numpy's exact f32 op sequence (verified absmax=0 in R1)
__device__ __forceinline__ void get_consts(float& bnd0, float& bnd1,
                                           float& tb0, float& tb1, float& thr) {
    const float bx0 = (float)(-30.0 + 0.15 / 2.0);
    const float bx1 = (float)(-15.0 + 0.15 / 2.0);
    bnd0 = __fsub_rn(__fmul_rn(0.15f, 0.5f), bx0);
    bnd1 = __fsub_rn(__fmul_rn(0.15f, 0.5f), bx1);
    tb0 = __fmul_rn(2.0f, bnd0); tb1 = __fmul_rn(2.0f, bnd1);
    const float q0 = __fdiv_rn(1.5f, tb0), q1 = __fdiv_rn(1.5f, tb1);
    thr = __fsqrt_rn(__fadd_rn(__fmul_rn(q0, q0), __fmul_rn(q1, q1)));
}

// ---------------------------------------------------------------------------
// Zero the matches_gt region of d_out: elements [3, 3+16*1025*1025)
// ---------------------------------------------------------------------------
__global__ void k_zero(float* __restrict__ out) {
    const long long idx = (long long)blockIdx.x * blockDim.x + threadIdx.x;
    const long long T   = (long long)gridDim.x * blockDim.x;
    float4* f4 = (float4*)(out + 4);
    const long long n4 = (16810000LL - 1) / 4;
    float4 z; z.x = 0.f; z.y = 0.f; z.z = 0.f; z.w = 0.f;
    for (long long k = idx; k < n4; k += T) f4[k] = z;
    if (idx == 0) {
        out[3] = 0.f;
        out[16810000] = 0.f; out[16810001] = 0.f; out[16810002] = 0.f;
    }
}

// ---------------------------------------------------------------------------
// K1: partial nearest-GT. grid (8 pchunk * 8 gsplit, 16 b) x 128.
// Packed key ((u64)cd_bits << 10) | g : min() == np.argmin first-index rule
// (cd > 0 so float bit order is monotone; ties in cd -> smaller g wins).
// ---------------------------------------------------------------------------
__global__ __launch_bounds__(128) void k_nearest1(
    const float* __restrict__ positions, const float* __restrict__ gt_pts,
    unsigned long long* __restrict__ part)
{
    __shared__ float2 sp[128];
    const int b = blockIdx.y;
    const int pc = blockIdx.x & 7, gs = blockIdx.x >> 3;
    const int tid = threadIdx.x;
    float bnd0, bnd1, tb0, tb1, thr;
    get_consts(bnd0, bnd1, tb0, tb1, thr);

    {
        const int g = (gs << 7) + tid;
        float2 gp = ((const float2*)gt_pts)[b * GG + g];
        float2 pg;
        pg.x = __fdiv_rn(__fadd_rn(gp.x, bnd0), tb0);
        pg.y = __fdiv_rn(__fadd_rn(gp.y, bnd1), tb1);
        sp[tid] = pg;
    }
    __syncthreads();

    const int i = (pc << 7) + tid;
    float2 p = ((const float2*)positions)[b * NN + i];
    const float px = __fdiv_rn(p.x, 399.0f);
    const float py = __fdiv_rn(p.y, 199.0f);

    unsigned long long best = ~0ull;
    const int gbase = gs << 7;
    #pragma unroll 8
    for (int g = 0; g < 128; ++g) {
        float2 pg = sp[g];
        float dx = __fsub_rn(px, pg.x);
        float dy = __fsub_rn(py, pg.y);
        float s  = __fadd_rn(__fadd_rn(__fmul_rn(dx, dx), __fmul_rn(dy, dy)), 1e-12f);
        float cd = __fsqrt_rn(s);
        unsigned long long pk =
            ((unsigned long long)__float_as_uint(cd) << 10) | (unsigned)(gbase + g);
        best = (pk < best) ? pk : best;
    }
    part[(((b << 3) + gs) << 10) + i] = best;
}

// ---------------------------------------------------------------------------
// K2: combine 8 partials -> nearest; build sort key, sem class, closs part;
// init tf/tb to NN. grid (8, 16) x 128.
// ---------------------------------------------------------------------------
__global__ __launch_bounds__(128) void k_combine(
    const float* __restrict__ positions, const float* __restrict__ gt_pts,
    const int* __restrict__ gt_ins, const int* __restrict__ gt_order,
    const int* __restrict__ gt_type,
    const unsigned long long* __restrict__ part,
    int* __restrict__ key_ws, int* __restrict__ sem_ws,
    int* __restrict__ tf_ws, int* __restrict__ tb_ws,
    float* __restrict__ closs_part)
{
    __shared__ float red[128];
    const int b = blockIdx.y, pc = blockIdx.x, tid = threadIdx.x;
    const int i = (pc << 7) + tid;
    float bnd0, bnd1, tb0, tb1, thr;
    get_consts(bnd0, bnd1, tb0, tb1, thr);

    unsigned long long best = part[((b << 3) << 10) + i];
    #pragma unroll
    for (int gs = 1; gs < 8; ++gs) {
        unsigned long long v = part[(((b << 3) + gs) << 10) + i];
        best = (v < best) ? v : best;
    }
    const int bi = (int)(best & 1023u);
    const float cd = __uint_as_float((unsigned)(best >> 10));

    const int ins = (cd < thr) ? gt_ins[b * GG + bi] : -1;
    const int key = ((ins + 1) << 15) | (gt_order[b * GG + bi] << 10) | i;
    key_ws[(b << 10) + i] = key;
    sem_ws[(b << 10) + i] = gt_type[b * GG + bi];
    tf_ws[(b << 10) + i] = NN;
    tb_ws[(b << 10) + i] = NN;

    float2 p = ((const float2*)positions)[b * NN + i];
    const float px = __fdiv_rn(p.x, 399.0f);
    const float py = __fdiv_rn(p.y, 199.0f);
    float2 gp = ((const float2*)gt_pts)[b * GG + bi];
    const float pgx = __fdiv_rn(__fadd_rn(gp.x, bnd0), tb0);
    const float pgy = __fdiv_rn(__fadd_rn(gp.y, bnd1), tb1);
    const float cl = fabsf(__fsub_rn(px, pgx)) + fabsf(__fsub_rn(py, pgy));

    red[tid] = cl; __syncthreads();
    for (int s = 64; s > 0; s >>= 1) {
        if (tid < s) red[tid] += red[tid + s];
        __syncthreads();
    }
    if (tid == 0) closs_part[(b << 3) + pc] = red[0];
}

// ---------------------------------------------------------------------------
// K3: rank-sort (keys unique: index in low 10 bits). Writes sorted keys.
// grid (8, 16) x 128; keys in LDS, int4 broadcast reads.
// ---------------------------------------------------------------------------
__global__ __launch_bounds__(128) void k_rank(
    const int* __restrict__ key_ws, int* __restrict__ sorted_ws)
{
    __shared__ int sk[NN];
    const int b = blockIdx.y, pc = blockIdx.x, tid = threadIdx.x;
    for (int j = tid; j < NN; j += 128) sk[j] = key_ws[(b << 10) + j];
    __syncthreads();
    const int k = sk[(pc << 7) + tid];
    int rank = 0;
    const int4* sk4 = (const int4*)sk;
    #pragma unroll 8
    for (int j = 0; j < 256; ++j) {
        int4 v = sk4[j];
        rank += (v.x < k) + (v.y < k) + (v.z < k) + (v.w < k);
    }
    sorted_ws[(b << 10) + rank] = k;
}

// ---------------------------------------------------------------------------
// K4: consecutive sorted pairs with same ins (>=0) -> edges.
// newblk == blk identity: each column of blk has <=1 nonzero, so the
// reference's dist_map/argmin re-selection is the identity (no dist_map!).
// grid (8, 16) x 128.
// ---------------------------------------------------------------------------
__global__ __launch_bounds__(128) void k_edges(
    const int* __restrict__ sorted_ws,
    int* __restrict__ tf_ws, int* __restrict__ tb_ws)
{
    const int b = blockIdx.y;
    const int p = (blockIdx.x << 7) + threadIdx.x;
    if (p >= NN - 1) return;
    const int k0 = sorted_ws[(b << 10) + p];
    const int k1 = sorted_ws[(b << 10) + p + 1];
    const int ia = (k0 >> 15) - 1;
    const int ic = (k1 >> 15) - 1;
    if (ia == ic && ia >= 0) {
        const int a = k0 & 1023, c = k1 & 1023;
        tf_ws[(b << 10) + a] = c;
        tb_ws[(b << 10) + c] = a;
    }
}

// ---------------------------------------------------------------------------
// K5: scatter M ones, write sg one-hot, gather match/semantic values,
// block-reduce mloss/semloss partials. grid (8, 16) x 128.
// ---------------------------------------------------------------------------
__global__ __launch_bounds__(128) void k_out(
    const float* __restrict__ matches, const float* __restrict__ semantics,
    const int* __restrict__ sem_ws,
    const int* __restrict__ tf_ws, const int* __restrict__ tb_ws,
    float* __restrict__ out, double* __restrict__ mpart, double* __restrict__ spart)
{
    __shared__ double redm[128], reds[128];
    const int b = blockIdx.y, pc = blockIdx.x, tid = threadIdx.x;
    const int i = (pc << 7) + tid;

    const int jf = tf_ws[(b << 10) + i];   // t_fwd[i]
    const int jb = tb_ws[(b << 10) + i];   // t_back[i]

    float* Mb = out + 3 + (size_t)b * NP1 * NP1;
    Mb[(size_t)i * NP1 + jf] = 1.0f;                 // row i: edge target or col N
    if (jb == NN) Mb[(size_t)NN * NP1 + i] = 1.0f;   // row N: cols w/o incoming edge

    const float* mrow = matches + (size_t)b * NP1 * NP1 + (size_t)i * NP1;
    const double mp = (double)mrow[jf] + (double)mrow[jb];

    const int sc = sem_ws[(b << 10) + i];
    const double sv = (double)semantics[(b * NC + sc) * NN + i];

    float* sg = out + 3 + (size_t)BB * NP1 * NP1 + (size_t)b * NC * NN;
    sg[0 * NN + i] = (sc == 0) ? 1.0f : 0.0f;
    sg[1 * NN + i] = (sc == 1) ? 1.0f : 0.0f;
    sg[2 * NN + i] = (sc == 2) ? 1.0f : 0.0f;

    redm[tid] = mp; reds[tid] = sv; __syncthreads();
    for (int s = 64; s > 0; s >>= 1) {
        if (tid < s) { redm[tid] += redm[tid + s]; reds[tid] += reds[tid + s]; }
        __syncthreads();
    }
    if (tid == 0) { mpart[(b << 3) + pc] = redm[0]; spart[(b << 3) + pc] = reds[0]; }
}

// ---------------------------------------------------------------------------
// K6: fold 128 partials each into the 3 scalar outputs.
// ---------------------------------------------------------------------------
__global__ __launch_bounds__(128) void k_final(
    const float* __restrict__ closs_part, const double* __restrict__ mpart,
    const double* __restrict__ spart, float* __restrict__ out)
{
    __shared__ double rc[128], rm[128], rs[128];
    const int t = threadIdx.x;
    rc[t] = (double)closs_part[t]; rm[t] = mpart[t]; rs[t] = spart[t];
    __syncthreads();
    for (int s = 64; s > 0; s >>= 1) {
        if (t < s) { rc[t] += rc[t + s]; rm[t] += rm[t + s]; rs[t] += rs[t + s]; }
        __syncthreads();
    }
    if (t == 0) {
        out[0] = (float)(rc[0] / 32768.0);    // mean over B of (sum/2048)
        out[1] = (float)(-rm[0] / 16384.0);   // mean over B of (sum_f/1024 + sum_b/1024)
        out[2] = (float)(-rs[0] / 16384.0);
    }
}

extern "C" void kernel_launch(void* const* d_in, const int* in_sizes, int n_in,
                              void* d_out, int out_size, void* d_ws, size_t ws_size,
                              hipStream_t stream) {
    const float* matches   = (const float*)d_in[0];
    const float* positions = (const float*)d_in[1];
    const float* semantics = (const float*)d_in[2];
    // d_in[3] = masks (all ones, unused)
    const float* gt_pts    = (const float*)d_in[4];
    const int*   gt_ins    = (const int*)d_in[5];
    const int*   gt_order  = (const int*)d_in[6];
    const int*   gt_type   = (const int*)d_in[7];
    float* out = (float*)d_out;

    char* ws = (char*)d_ws;
    unsigned long long* part = (unsigned long long*)ws;          // 16*8*1024 u64 = 1 MB
    int*    key_ws     = (int*)(ws + (1 << 20));                 // 64 KB
    int*    sem_ws     = (int*)(ws + (1 << 20) + (1 << 16));     // 64 KB
    int*    sorted_ws  = (int*)(ws + (1 << 20) + (2 << 16));     // 64 KB
    int*    tf_ws      = (int*)(ws + (1 << 20) + (3 << 16));     // 64 KB
    int*    tb_ws      = (int*)(ws + (1 << 20) + (4 << 16));     // 64 KB
    float*  closs_part = (float*)(ws + (1 << 20) + (5 << 16));   // 512 B
    double* mpart      = (double*)(ws + (1 << 20) + (5 << 16) + 1024);
    double* spart      = (double*)(ws + (1 << 20) + (5 << 16) + 2048);

    hipLaunchKernelGGL(k_zero,     dim3(2048),    dim3(256), 0, stream, out);
    hipLaunchKernelGGL(k_nearest1, dim3(64, 16),  dim3(128), 0, stream,
                       positions, gt_pts, part);
    hipLaunchKernelGGL(k_combine,  dim3(8, 16),   dim3(128), 0, stream,
                       positions, gt_pts, gt_ins, gt_order, gt_type, part,
                       key_ws, sem_ws, tf_ws, tb_ws, closs_part);
    hipLaunchKernelGGL(k_rank,     dim3(8, 16),   dim3(128), 0, stream, key_ws, sorted_ws);
    hipLaunchKernelGGL(k_edges,    dim3(8, 16),   dim3(128), 0, stream, sorted_ws, tf_ws, tb_ws);
    hipLaunchKernelGGL(k_out,      dim3(8, 16),   dim3(128), 0, stream,
                       matches, semantics, sem_ws, tf_ws, tb_ws, out, mpart, spart);
    hipLaunchKernelGGL(k_final,    dim3(1),       dim3(128), 0, stream,
                       closs_part, mpart, spart, out);
}

// Round 3
// 148.905 us; speedup vs baseline: 1.2750x; 1.0342x over previous
//
#include <hip/hip_runtime.h>
#include <math.h>

#define BB 16
#define NN 1024
#define GG 1024
#define NP1 1025
#define NC 3

// Constants replicated with numpy's exact f32 op sequence (verified absmax=0 in R1/R2)
__device__ __forceinline__ void get_consts(float& bnd0, float& bnd1,
                                           float& tb0, float& tb1, float& thr) {
    const float bx0 = (float)(-30.0 + 0.15 / 2.0);
    const float bx1 = (float)(-15.0 + 0.15 / 2.0);
    bnd0 = __fsub_rn(__fmul_rn(0.15f, 0.5f), bx0);
    bnd1 = __fsub_rn(__fmul_rn(0.15f, 0.5f), bx1);
    tb0 = __fmul_rn(2.0f, bnd0); tb1 = __fmul_rn(2.0f, bnd1);
    const float q0 = __fdiv_rn(1.5f, tb0), q1 = __fdiv_rn(1.5f, tb1);
    thr = __fsqrt_rn(__fadd_rn(__fmul_rn(q0, q0), __fmul_rn(q1, q1)));
}

// ---------------------------------------------------------------------------
// K1: fused nearest-GT + key build. grid (16 pc, 16 b) x 512.
// Thread (gs=tid>>6, sub=tid&63) scans GT slice [gs*128, gs*128+128) for
// position i = pc*64+sub; 8-way LDS min-tree on packed ((u64)cd_bits<<10)|g
// reproduces np.argmin first-index tie rule (min over g, cd>0 => bit-monotone).
// gs==0 lanes then build sort key / sem class / tf-tb init / closs partial.
// ---------------------------------------------------------------------------
__global__ __launch_bounds__(512) void k_near(
    const float* __restrict__ positions, const float* __restrict__ gt_pts,
    const int* __restrict__ gt_ins, const int* __restrict__ gt_order,
    const int* __restrict__ gt_type,
    int* __restrict__ key_ws, int* __restrict__ sem_ws,
    int* __restrict__ tf_ws, int* __restrict__ tb_ws,
    float* __restrict__ closs_part)
{
    __shared__ float2 sp[GG];
    __shared__ unsigned long long pl[512];
    const int b = blockIdx.y, pc = blockIdx.x, tid = threadIdx.x;
    const int sub = tid & 63, gs = tid >> 6;
    float bnd0, bnd1, tb0, tb1, thr;
    get_consts(bnd0, bnd1, tb0, tb1, thr);

    for (int g = tid; g < GG; g += 512) {
        float2 gp = ((const float2*)gt_pts)[b * GG + g];
        float2 pg;
        pg.x = __fdiv_rn(__fadd_rn(gp.x, bnd0), tb0);
        pg.y = __fdiv_rn(__fadd_rn(gp.y, bnd1), tb1);
        sp[g] = pg;
    }
    __syncthreads();

    const int i = (pc << 6) + sub;
    float2 p = ((const float2*)positions)[b * NN + i];
    const float px = __fdiv_rn(p.x, 399.0f);
    const float py = __fdiv_rn(p.y, 199.0f);

    unsigned long long best = ~0ull;
    const int gbase = gs << 7;
    #pragma unroll 8
    for (int j = 0; j < 128; ++j) {
        float2 pg = sp[gbase + j];
        float dx = __fsub_rn(px, pg.x);
        float dy = __fsub_rn(py, pg.y);
        float s  = __fadd_rn(__fadd_rn(__fmul_rn(dx, dx), __fmul_rn(dy, dy)), 1e-12f);
        float cd = __fsqrt_rn(s);
        unsigned long long pk =
            ((unsigned long long)__float_as_uint(cd) << 10) | (unsigned)(gbase + j);
        best = (pk < best) ? pk : best;
    }
    pl[tid] = best;
    __syncthreads();
    #pragma unroll
    for (int s = 4; s > 0; s >>= 1) {
        if (gs < s) {
            unsigned long long v = pl[tid + (s << 6)];
            if (v < pl[tid]) pl[tid] = v;
        }
        __syncthreads();
    }

    if (tid < 64) {
        best = pl[tid];
        const int bi = (int)(best & 1023u);
        const float cd = __uint_as_float((unsigned)(best >> 10));

        const int ins = (cd < thr) ? gt_ins[b * GG + bi] : -1;
        const int key = ((ins + 1) << 15) | (gt_order[b * GG + bi] << 10) | i;
        key_ws[(b << 10) + i] = key;
        sem_ws[(b << 10) + i] = gt_type[b * GG + bi];
        tf_ws[(b << 10) + i] = NN;
        tb_ws[(b << 10) + i] = NN;

        float2 pg = sp[bi];
        float cl = fabsf(__fsub_rn(px, pg.x)) + fabsf(__fsub_rn(py, pg.y));
        #pragma unroll
        for (int s = 32; s > 0; s >>= 1) cl += __shfl_down(cl, s);
        if (tid == 0) closs_part[(b << 4) + pc] = cl;
    }
}

// ---------------------------------------------------------------------------
// K2: rank-sort (keys unique: index in low 10 bits). grid (8,16) x 128.
// ---------------------------------------------------------------------------
__global__ __launch_bounds__(128) void k_rank(
    const int* __restrict__ key_ws, int* __restrict__ sorted_ws)
{
    __shared__ int sk[NN];
    const int b = blockIdx.y, pc = blockIdx.x, tid = threadIdx.x;
    for (int j = tid; j < NN; j += 128) sk[j] = key_ws[(b << 10) + j];
    __syncthreads();
    const int k = sk[(pc << 7) + tid];
    int rank = 0;
    const int4* sk4 = (const int4*)sk;
    #pragma unroll 8
    for (int j = 0; j < 256; ++j) {
        int4 v = sk4[j];
        rank += (v.x < k) + (v.y < k) + (v.z < k) + (v.w < k);
    }
    sorted_ws[(b << 10) + rank] = k;
}

// ---------------------------------------------------------------------------
// K3: consecutive sorted pairs, same ins (>=0) -> edges. grid (2,16) x 512.
// (newblk == blk identity: each blk column has <=1 nonzero, so the reference's
// dist_map/argmin re-selection is the identity -> no dist_map needed.)
// ---------------------------------------------------------------------------
__global__ __launch_bounds__(512) void k_edges(
    const int* __restrict__ sorted_ws,
    int* __restrict__ tf_ws, int* __restrict__ tb_ws)
{
    const int b = blockIdx.y;
    const int p = (blockIdx.x << 9) + threadIdx.x;
    if (p >= NN - 1) return;
    const int k0 = sorted_ws[(b << 10) + p];
    const int k1 = sorted_ws[(b << 10) + p + 1];
    const int ia = (k0 >> 15) - 1;
    const int ic = (k1 >> 15) - 1;
    if (ia == ic && ia >= 0) {
        const int a = k0 & 1023, c = k1 & 1023;
        tf_ws[(b << 10) + a] = c;
        tb_ws[(b << 10) + c] = a;
    }
}

// ---------------------------------------------------------------------------
// K4: fused M writer. grid (32 pc, 16 b) x 256.
// Phase A: zero the block's 32-row slab of M densely (float4, coalesced).
// Phase B: ones at (i, tf[i]); dense row-N from tb; sg one-hot; wave-reduce
// mloss/semloss partials. Every byte of d_out's M region written exactly once.
// ---------------------------------------------------------------------------
__global__ __launch_bounds__(256) void k_out(
    const float* __restrict__ matches, const float* __restrict__ semantics,
    const int* __restrict__ sem_ws,
    const int* __restrict__ tf_ws, const int* __restrict__ tb_ws,
    float* __restrict__ out, double* __restrict__ mpart, double* __restrict__ spart)
{
    const int b = blockIdx.y, pc = blockIdx.x, tid = threadIdx.x;
    float* Mb = out + 3 + (size_t)b * NP1 * NP1;

    // Phase A: zero rows [pc*32, pc*32+32) = 32*1025 floats
    {
        float* base = Mb + (size_t)pc * 32 * NP1;
        const int total = 32 * NP1;                       // 32800
        const int mis = (int)(((size_t)base >> 2) & 3);   // floats to 16B align
        const int head = (4 - mis) & 3;
        const int n4 = (total - head) >> 2;
        const int tail = total - head - (n4 << 2);
        if (tid < head) base[tid] = 0.f;
        float4* b4 = (float4*)(base + head);
        float4 z; z.x = 0.f; z.y = 0.f; z.z = 0.f; z.w = 0.f;
        for (int k = tid; k < n4; k += 256) b4[k] = z;
        if (tid < tail) base[head + (n4 << 2) + tid] = 0.f;
    }
    __syncthreads();

    // Phase B: first wave handles the block's 32 columns/rows
    if (tid < 64) {
        double mv = 0.0, sv = 0.0;
        if (tid < 32) {
            const int i = (pc << 5) + tid;
            const int jf = tf_ws[(b << 10) + i];
            const int jb = tb_ws[(b << 10) + i];

            Mb[(size_t)i * NP1 + jf] = 1.0f;                       // row i
            Mb[(size_t)NN * NP1 + i] = (jb == NN) ? 1.0f : 0.0f;   // row N dense
            if (pc == 0 && tid == 0) Mb[(size_t)NN * NP1 + NN] = 0.f;

            const float* mrow = matches + (size_t)b * NP1 * NP1 + (size_t)i * NP1;
            mv = (double)mrow[jf] + (double)mrow[jb];

            const int sc = sem_ws[(b << 10) + i];
            sv = (double)semantics[(b * NC + sc) * NN + i];

            float* sg = out + 3 + (size_t)BB * NP1 * NP1 + (size_t)b * NC * NN;
            sg[0 * NN + i] = (sc == 0) ? 1.0f : 0.0f;
            sg[1 * NN + i] = (sc == 1) ? 1.0f : 0.0f;
            sg[2 * NN + i] = (sc == 2) ? 1.0f : 0.0f;
        }
        #pragma unroll
        for (int s = 32; s > 0; s >>= 1) {
            mv += __shfl_down(mv, s);
            sv += __shfl_down(sv, s);
        }
        if (tid == 0) {
            mpart[(b << 5) + pc] = mv;
            spart[(b << 5) + pc] = sv;
        }
    }
}

// ---------------------------------------------------------------------------
// K5: fold partials (256 closs, 512 m, 512 s) into the 3 scalars.
// ---------------------------------------------------------------------------
__global__ __launch_bounds__(512) void k_final(
    const float* __restrict__ closs_part, const double* __restrict__ mpart,
    const double* __restrict__ spart, float* __restrict__ out)
{
    __shared__ double rc[512], rm[512], rs[512];
    const int t = threadIdx.x;
    rc[t] = (t < 256) ? (double)closs_part[t] : 0.0;
    rm[t] = mpart[t]; rs[t] = spart[t];
    __syncthreads();
    for (int s = 256; s > 0; s >>= 1) {
        if (t < s) { rc[t] += rc[t + s]; rm[t] += rm[t + s]; rs[t] += rs[t + s]; }
        __syncthreads();
    }
    if (t == 0) {
        out[0] = (float)(rc[0] / 32768.0);    // mean over B of (sum/2048)
        out[1] = (float)(-rm[0] / 16384.0);   // mean over B of (sum_f + sum_b)/1024
        out[2] = (float)(-rs[0] / 16384.0);
    }
}

extern "C" void kernel_launch(void* const* d_in, const int* in_sizes, int n_in,
                              void* d_out, int out_size, void* d_ws, size_t ws_size,
                              hipStream_t stream) {
    const float* matches   = (const float*)d_in[0];
    const float* positions = (const float*)d_in[1];
    const float* semantics = (const float*)d_in[2];
    // d_in[3] = masks (all ones, unused)
    const float* gt_pts    = (const float*)d_in[4];
    const int*   gt_ins    = (const int*)d_in[5];
    const int*   gt_order  = (const int*)d_in[6];
    const int*   gt_type   = (const int*)d_in[7];
    float* out = (float*)d_out;

    char* ws = (char*)d_ws;
    int*    key_ws     = (int*)(ws + 0 * 65536);
    int*    sem_ws     = (int*)(ws + 1 * 65536);
    int*    sorted_ws  = (int*)(ws + 2 * 65536);
    int*    tf_ws      = (int*)(ws + 3 * 65536);
    int*    tb_ws      = (int*)(ws + 4 * 65536);
    float*  closs_part = (float*)(ws + 5 * 65536);            // 256 floats
    double* mpart      = (double*)(ws + 5 * 65536 + 4096);    // 512 doubles
    double* spart      = (double*)(ws + 5 * 65536 + 8192);    // 512 doubles

    hipLaunchKernelGGL(k_near,  dim3(16, 16), dim3(512), 0, stream,
                       positions, gt_pts, gt_ins, gt_order, gt_type,
                       key_ws, sem_ws, tf_ws, tb_ws, closs_part);
    hipLaunchKernelGGL(k_rank,  dim3(8, 16),  dim3(128), 0, stream, key_ws, sorted_ws);
    hipLaunchKernelGGL(k_edges, dim3(2, 16),  dim3(512), 0, stream, sorted_ws, tf_ws, tb_ws);
    hipLaunchKernelGGL(k_out,   dim3(32, 16), dim3(256), 0, stream,
                       matches, semantics, sem_ws, tf_ws, tb_ws, out, mpart, spart);
    hipLaunchKernelGGL(k_final, dim3(1),      dim3(512), 0, stream,
                       closs_part, mpart, spart, out);
}